// Round 7
// baseline (249.566 us; speedup 1.0000x reference)
//
#include <hip/hip_runtime.h>

#define N_NODES 100000
#define N_EDGES 1600000
#define IN_DIM  128
#define HIDDEN  128
#define OUT_DIM 64

#define NB_COARSE ((N_NODES + 255) / 256)   // 391 coarse buckets (256 nodes each)
#define EPB 16384                           // edges per block in k_part (long runs)
#define NBLK_E ((N_EDGES + EPB - 1) / EPB)  // 98 blocks
#define CAP 5120                            // fixed bucket capacity (mean 4092 + 16 sigma)
#define PCAP 6912                           // padded bucket capacity, mult of 8

typedef __attribute__((ext_vector_type(8))) short bf8_t;   // 8 x bf16 (4 VGPRs)
typedef __attribute__((ext_vector_type(4))) float f4_t;    // MFMA accumulator

__device__ __forceinline__ ushort f2b(float f) {           // fp32 -> bf16 RNE
    unsigned int u = __float_as_uint(f);
    u += 0x7fffu + ((u >> 16) & 1u);
    return (ushort)(u >> 16);
}
__device__ __forceinline__ float b2f_lo(unsigned int u) { return __uint_as_float(u << 16); }
__device__ __forceinline__ float b2f_hi(unsigned int u) { return __uint_as_float(u & 0xffff0000u); }

// ---- prep: transpose W1/W2 to bf16 n-major; init cursors; zero h sentinel row ----

__global__ __launch_bounds__(512) void k_prep(const float* __restrict__ W1,
                                              const float* __restrict__ W2,
                                              int* __restrict__ cursor,
                                              ushort* __restrict__ W1T,
                                              ushort* __restrict__ W2T,
                                              unsigned int* __restrict__ hz) {
    int idx = blockIdx.x * 512 + threadIdx.x;
    if (idx < 16384) {                       // W1 [k][n] 128x128 -> W1T [n][k] bf16
        int k = idx >> 7, n = idx & 127;
        W1T[n * 128 + k] = f2b(W1[idx]);
    } else if (idx < 24576) {                // W2 [k][n] 128x64 -> W2T [n][k] bf16
        int j = idx - 16384;
        int k = j >> 6, n = j & 63;
        W2T[n * 128 + k] = f2b(W2[j]);
    } else if (idx < 24576 + NB_COARSE) {
        cursor[idx - 24576] = (idx - 24576) * CAP;
    } else if (idx < 24576 + NB_COARSE + 64) {
        hz[(size_t)N_NODES * 64 + (idx - 24576 - NB_COARSE)] = 0u;  // bf16 zero row
    }
}

// ---- single-pass bucketed partition, 16K edges/block (long store runs) ----

__global__ __launch_bounds__(256) void k_part(const int* __restrict__ ei,
                                              int* __restrict__ cursor,
                                              unsigned int* __restrict__ part) {
    __shared__ int lh[NB_COARSE];     // local hist, then local cursor
    __shared__ int lbase[NB_COARSE];  // global base of this block's run per bucket
    int t = threadIdx.x;
    for (int i = t; i < NB_COARSE; i += 256) lh[i] = 0;
    __syncthreads();
    int e0 = blockIdx.x * EPB;
    int eend = min(e0 + EPB, N_EDGES);
    for (int e = e0 + t; e < eend; e += 256)
        atomicAdd(&lh[ei[N_EDGES + e] >> 8], 1);
    __syncthreads();
    for (int i = t; i < NB_COARSE; i += 256) {
        int c = lh[i];
        lbase[i] = (c > 0) ? atomicAdd(&cursor[i], c) : 0;
        lh[i] = 0;                    // becomes local cursor
    }
    __syncthreads();
    for (int e = e0 + t; e < eend; e += 256) {
        int d = ei[N_EDGES + e];
        int s = ei[e];
        int b = d >> 8;
        int pos = lbase[b] + atomicAdd(&lh[b], 1);
        part[pos] = ((unsigned int)(d & 255) << 24) | (unsigned int)s;
    }
}

// ------- per-bucket CSR finalize: padded per-node ranges (pad -> sentinel N_NODES) -------

__global__ __launch_bounds__(256) void k_csr(const unsigned int* __restrict__ part,
                                             const int* __restrict__ cursor,
                                             int* __restrict__ offs,
                                             int* __restrict__ pcnt,
                                             float* __restrict__ dinv,
                                             int* __restrict__ ssrc) {
    __shared__ int ldeg[256], lsc[256], lcur[256], sob[256];
    __shared__ unsigned int stage[CAP];
    int t = threadIdx.x;
    int b = blockIdx.x;
    int rbeg = b * CAP;
    int cnt = cursor[b] - rbeg;       // edges landed in this bucket
    int node0 = b << 8;
    ldeg[t] = 0;
    __syncthreads();
    for (int i = t; i < cnt; i += 256) {
        unsigned int u = part[rbeg + i];
        stage[i] = u;
        atomicAdd(&ldeg[u >> 24], 1);
    }
    __syncthreads();
    int v = ldeg[t];
    int pv = (v + 7) & ~7;            // padded to multiple of 8
    lsc[t] = pv;
    __syncthreads();
    for (int off = 1; off < 256; off <<= 1) {
        int add = (t >= off) ? lsc[t - off] : 0;
        __syncthreads();
        lsc[t] += add;
        __syncthreads();
    }
    int ob = b * PCAP + (lsc[t] - pv);   // padded output base for node (node0+t)
    sob[t] = ob;
    lcur[t] = 0;
    if (node0 + t < N_NODES) {
        offs[node0 + t] = ob;
        pcnt[node0 + t] = pv;
        dinv[node0 + t] = rsqrtf((float)(v + 1));   // +1: self-loop
    }
    __syncthreads();
    for (int i = t; i < cnt; i += 256) {
        unsigned int u = stage[i];
        int d = u >> 24;
        int pos = atomicAdd(&lcur[d], 1);
        ssrc[sob[d] + pos] = (int)(u & 0xFFFFFFu);
    }
    for (int i = v; i < pv; i++) ssrc[ob + i] = N_NODES;   // sentinel pads (zero row)
}

// ---------------- bf16 MFMA GEMM1: h = (x @ W1) * dinv[row], bf16 out ----------------

__global__ __launch_bounds__(256, 2) void k_mfma1(const float* __restrict__ A,
                                                  const ushort* __restrict__ WT,
                                                  const float* __restrict__ dinv,
                                                  ushort* __restrict__ C, int M) {
    constexpr int BM = 128, KK = 128, PAD = 8, BN = 128, MF = 4, NF = 4;
    __shared__ ushort As[BM][KK + PAD];
    __shared__ ushort Bs[BN][KK + PAD];

    int tid = threadIdx.x;
    int row0 = blockIdx.x * BM;

    #pragma unroll
    for (int i = 0; i < 16; i++) {
        int li = tid + i * 256;
        int r = li >> 5, c4 = li & 31;
        int grow = row0 + r; if (grow > M - 1) grow = M - 1;
        float4 v = *(const float4*)(A + (size_t)grow * KK + c4 * 4);
        ushort4 o;
        o.x = f2b(v.x); o.y = f2b(v.y); o.z = f2b(v.z); o.w = f2b(v.w);
        *(ushort4*)&As[r][c4 * 4] = o;
    }
    #pragma unroll
    for (int i = 0; i < 8; i++) {
        int li = tid + i * 256;           // 128 rows x 16 uint4
        int n = li >> 4, k8 = li & 15;
        *(uint4*)&Bs[n][k8 * 8] = *(const uint4*)(WT + (size_t)n * 128 + k8 * 8);
    }
    __syncthreads();

    int wave = tid >> 6, lane = tid & 63;
    int lr = lane & 15, lq = lane >> 4;
    int wm0 = (wave & 1) * 64;
    int wn0 = (wave >> 1) * 64;

    f4_t acc[MF][NF];
    #pragma unroll
    for (int mi = 0; mi < MF; mi++)
        #pragma unroll
        for (int ni = 0; ni < NF; ni++) acc[mi][ni] = (f4_t){0.f, 0.f, 0.f, 0.f};

    #pragma unroll
    for (int kb = 0; kb < 4; kb++) {
        bf8_t af[MF], bfr[NF];
        #pragma unroll
        for (int mi = 0; mi < MF; mi++)
            af[mi] = *(const bf8_t*)&As[wm0 + mi * 16 + lr][kb * 32 + lq * 8];
        #pragma unroll
        for (int ni = 0; ni < NF; ni++)
            bfr[ni] = *(const bf8_t*)&Bs[wn0 + ni * 16 + lr][kb * 32 + lq * 8];
        #pragma unroll
        for (int mi = 0; mi < MF; mi++)
            #pragma unroll
            for (int ni = 0; ni < NF; ni++)
                acc[mi][ni] = __builtin_amdgcn_mfma_f32_16x16x32_bf16(
                    af[mi], bfr[ni], acc[mi][ni], 0, 0, 0);
    }

    #pragma unroll
    for (int mi = 0; mi < MF; mi++) {
        #pragma unroll
        for (int r = 0; r < 4; r++) {
            int row = row0 + wm0 + mi * 16 + lq * 4 + r;
            if (row < M) {
                float dv = dinv[row];
                #pragma unroll
                for (int ni = 0; ni < NF; ni++)
                    C[(size_t)row * BN + wn0 + ni * 16 + lr] = f2b(acc[mi][ni][r] * dv);
            }
        }
    }
}

// ---------------- bf16 MFMA GEMM2: out = h2 @ W2 + b2 (fp32 out) ----------------

__global__ __launch_bounds__(256, 2) void k_mfma2(const ushort* __restrict__ A,
                                                  const ushort* __restrict__ WT,
                                                  const float* __restrict__ bias,
                                                  float* __restrict__ C, int M) {
    constexpr int BM = 128, KK = 128, PAD = 8, BN = 64, MF = 2, NF = 4;
    __shared__ ushort As[BM][KK + PAD];
    __shared__ ushort Bs[BN][KK + PAD];

    int tid = threadIdx.x;
    int row0 = blockIdx.x * BM;

    #pragma unroll
    for (int i = 0; i < 8; i++) {
        int li = tid + i * 256;           // 128*16 uint4 loads
        int r = li >> 4, c8 = li & 15;
        int grow = row0 + r; if (grow > M - 1) grow = M - 1;
        uint4 v = *(const uint4*)(A + (size_t)grow * KK + c8 * 8);
        *(uint4*)&As[r][c8 * 8] = v;
    }
    #pragma unroll
    for (int i = 0; i < 4; i++) {
        int li = tid + i * 256;           // 64 rows x 16 uint4
        int n = li >> 4, k8 = li & 15;
        *(uint4*)&Bs[n][k8 * 8] = *(const uint4*)(WT + (size_t)n * 128 + k8 * 8);
    }
    __syncthreads();

    int wave = tid >> 6, lane = tid & 63;
    int lr = lane & 15, lq = lane >> 4;
    int wm0 = wave * 32;

    f4_t acc[MF][NF];
    #pragma unroll
    for (int mi = 0; mi < MF; mi++)
        #pragma unroll
        for (int ni = 0; ni < NF; ni++) acc[mi][ni] = (f4_t){0.f, 0.f, 0.f, 0.f};

    #pragma unroll
    for (int kb = 0; kb < 4; kb++) {
        bf8_t af[MF], bfr[NF];
        #pragma unroll
        for (int mi = 0; mi < MF; mi++)
            af[mi] = *(const bf8_t*)&As[wm0 + mi * 16 + lr][kb * 32 + lq * 8];
        #pragma unroll
        for (int ni = 0; ni < NF; ni++)
            bfr[ni] = *(const bf8_t*)&Bs[ni * 16 + lr][kb * 32 + lq * 8];
        #pragma unroll
        for (int mi = 0; mi < MF; mi++)
            #pragma unroll
            for (int ni = 0; ni < NF; ni++)
                acc[mi][ni] = __builtin_amdgcn_mfma_f32_16x16x32_bf16(
                    af[mi], bfr[ni], acc[mi][ni], 0, 0, 0);
    }

    #pragma unroll
    for (int mi = 0; mi < MF; mi++) {
        #pragma unroll
        for (int r = 0; r < 4; r++) {
            int row = row0 + wm0 + mi * 16 + lq * 4 + r;
            if (row < M) {
                #pragma unroll
                for (int ni = 0; ni < NF; ni++) {
                    int col = ni * 16 + lr;
                    C[(size_t)row * BN + col] = acc[mi][ni][r] + bias[col];
                }
            }
        }
    }
}

// -------- aggregation: h2[n] = bf16(relu(b1 + dinv[n]*(hs[n] + sum_s hs[s]))) --------
// One wave per node, lane-per-uint (R4 layout: best measured). Edge lists padded
// to multiples of 8 with sentinel N_NODES (zero row); 8-edge pipelined gathers.

__global__ __launch_bounds__(256) void k_agg(const ushort* __restrict__ h,
                                             const int* __restrict__ offs,
                                             const int* __restrict__ pcnt,
                                             const int* __restrict__ ssrc,
                                             const float* __restrict__ dinv,
                                             const float* __restrict__ b1,
                                             ushort* __restrict__ h2) {
    int wave = threadIdx.x >> 6;
    int lane = threadIdx.x & 63;
    int n = blockIdx.x * 4 + wave;
    if (n >= N_NODES) return;

    const unsigned int* hp = (const unsigned int*)h;  // 2 bf16 per uint, 64 uints/row
    int e0 = offs[n];
    int iters = pcnt[n] >> 3;
    const uint4* ip = (const uint4*)(ssrc + e0);      // 32B-aligned (e0 mult of 8)

    float ax0 = 0.f, ay0 = 0.f, ax1 = 0.f, ay1 = 0.f;
    float ax2 = 0.f, ay2 = 0.f, ax3 = 0.f, ay3 = 0.f;
    uint4 i0, i1;
    if (iters > 0) { i0 = ip[0]; i1 = ip[1]; }
    for (int it = 0; it < iters; it++) {
        uint4 nx0 = i0, nx1 = i1;
        if (it + 1 < iters) { nx0 = ip[(it + 1) * 2]; nx1 = ip[(it + 1) * 2 + 1]; }
        unsigned int u0 = hp[i0.x * 64 + lane];
        unsigned int u1 = hp[i0.y * 64 + lane];
        unsigned int u2 = hp[i0.z * 64 + lane];
        unsigned int u3 = hp[i0.w * 64 + lane];
        unsigned int u4 = hp[i1.x * 64 + lane];
        unsigned int u5 = hp[i1.y * 64 + lane];
        unsigned int u6 = hp[i1.z * 64 + lane];
        unsigned int u7 = hp[i1.w * 64 + lane];
        ax0 += b2f_lo(u0); ay0 += b2f_hi(u0);
        ax1 += b2f_lo(u1); ay1 += b2f_hi(u1);
        ax2 += b2f_lo(u2); ay2 += b2f_hi(u2);
        ax3 += b2f_lo(u3); ay3 += b2f_hi(u3);
        ax0 += b2f_lo(u4); ay0 += b2f_hi(u4);
        ax1 += b2f_lo(u5); ay1 += b2f_hi(u5);
        ax2 += b2f_lo(u6); ay2 += b2f_hi(u6);
        ax3 += b2f_lo(u7); ay3 += b2f_hi(u7);
        i0 = nx0; i1 = nx1;
    }
    unsigned int us = hp[(size_t)n * 64 + lane];      // self term: hs[n]*dinv[n]
    float dn = dinv[n];
    float rx = (ax0 + ax1 + ax2 + ax3 + b2f_lo(us)) * dn;
    float ry = (ay0 + ay1 + ay2 + ay3 + b2f_hi(us)) * dn;
    float2 bb = ((const float2*)b1)[lane];
    rx += bb.x; ry += bb.y;
    rx = rx > 0.f ? rx : 0.f;
    ry = ry > 0.f ? ry : 0.f;
    unsigned int o = ((unsigned int)f2b(ry) << 16) | (unsigned int)f2b(rx);
    ((unsigned int*)h2)[(size_t)n * 64 + lane] = o;
}

// ---------------- launch ----------------

extern "C" void kernel_launch(void* const* d_in, const int* in_sizes, int n_in,
                              void* d_out, int out_size, void* d_ws, size_t ws_size,
                              hipStream_t stream) {
    const float* x  = (const float*)d_in[0];
    const float* W1 = (const float*)d_in[1];
    const float* b1 = (const float*)d_in[2];
    const float* W2 = (const float*)d_in[3];
    const float* b2 = (const float*)d_in[4];
    const int*   ei = (const int*)d_in[5];
    float* out = (float*)d_out;

    char* w = (char*)d_ws;
    size_t off = 0;
    auto alloc = [&](size_t bytes) -> void* {
        void* p = w + off;
        off += (bytes + 255) & ~(size_t)255;
        return p;
    };
    ushort* h      = (ushort*)alloc((size_t)(N_NODES + 1) * HIDDEN * 2);  // +1 sentinel row
    ushort* h2     = (ushort*)alloc((size_t)N_NODES * HIDDEN * 2);
    float* dinv    = (float*)alloc((size_t)N_NODES * 4);
    int*   offs    = (int*)alloc((size_t)N_NODES * 4);
    int*   pcnt    = (int*)alloc((size_t)N_NODES * 4);
    int*   ssrc    = (int*)alloc((size_t)NB_COARSE * PCAP * 4);
    unsigned int* part = (unsigned int*)alloc((size_t)NB_COARSE * CAP * 4);
    int*   cursor  = (int*)alloc((size_t)NB_COARSE * 4);
    ushort* W1T    = (ushort*)alloc((size_t)128 * 128 * 2);
    ushort* W2T    = (ushort*)alloc((size_t)64 * 128 * 2);

    k_prep<<<49, 512, 0, stream>>>(W1, W2, cursor, W1T, W2T, (unsigned int*)h);
    k_part<<<NBLK_E, 256, 0, stream>>>(ei, cursor, part);
    k_csr<<<NB_COARSE, 256, 0, stream>>>(part, cursor, offs, pcnt, dinv, ssrc);

    k_mfma1<<<(N_NODES + 127) / 128, 256, 0, stream>>>(x, W1T, dinv, h, N_NODES);
    k_agg<<<(N_NODES + 3) / 4, 256, 0, stream>>>(h, offs, pcnt, ssrc, dinv, b1, h2);
    k_mfma2<<<(N_NODES + 127) / 128, 256, 0, stream>>>(h2, W2T, b2, out, N_NODES);
}

// Round 8
// 225.873 us; speedup vs baseline: 1.1049x; 1.1049x over previous
//
#include <hip/hip_runtime.h>

#define N_NODES 100000
#define N_EDGES 1600000
#define IN_DIM  128
#define HIDDEN  128
#define OUT_DIM 64

#define NB_COARSE ((N_NODES + 255) / 256)   // 391 coarse buckets (256 nodes each)
#define EPB 4096                            // edges per block in partition role
#define NBLK_E ((N_EDGES + EPB - 1) / EPB)  // 391 partition blocks
#define GB1 ((N_NODES + 127) / 128)         // 782 GEMM1 blocks
#define CAP 5120                            // fixed bucket capacity (mean 4092 + 16 sigma)
#define PCAP 6912                           // padded bucket capacity, mult of 8

typedef __attribute__((ext_vector_type(8))) short bf8_t;   // 8 x bf16 (4 VGPRs)
typedef __attribute__((ext_vector_type(4))) float f4_t;    // MFMA accumulator

__device__ __forceinline__ ushort f2b(float f) {           // fp32 -> bf16 RNE
    unsigned int u = __float_as_uint(f);
    u += 0x7fffu + ((u >> 16) & 1u);
    return (ushort)(u >> 16);
}
__device__ __forceinline__ float b2f_lo(unsigned int u) { return __uint_as_float(u << 16); }
__device__ __forceinline__ float b2f_hi(unsigned int u) { return __uint_as_float(u & 0xffff0000u); }

// ---- fused launch 1: partition role (blocks 0..390) + GEMM1 role (391..1172) ----
// Roles are independent: partition is atomic/memory-bound, GEMM1 is MFMA-bound;
// co-scheduling hides the partition under the GEMM. h is UNSCALED bf16 (dinv
// applied per-edge in k_agg), which breaks the dinv->GEMM1 dependency.

__global__ __launch_bounds__(256, 2) void k_fuse1(const int* __restrict__ ei,
                                                  int* __restrict__ cursor,
                                                  unsigned int* __restrict__ part,
                                                  const float* __restrict__ x,
                                                  const float* __restrict__ W1,
                                                  ushort* __restrict__ h) {
    __shared__ __align__(16) ushort smem[2 * 128 * 136];   // 69632 B union
    int tid = threadIdx.x;

    if (blockIdx.x < NBLK_E) {
        // ---------- partition role (R4-proven structure) ----------
        int* lh    = (int*)smem;             // local hist, then local cursor
        int* lbase = lh + NB_COARSE;         // global base of this block's run
        for (int i = tid; i < NB_COARSE; i += 256) lh[i] = 0;
        __syncthreads();
        int e0 = blockIdx.x * EPB;
        int srcv[EPB / 256], dstv[EPB / 256];
        #pragma unroll
        for (int j = 0; j < EPB / 256; j++) {
            int e = e0 + j * 256 + tid;
            if (e < N_EDGES) {
                srcv[j] = ei[e];
                dstv[j] = ei[N_EDGES + e];
                atomicAdd(&lh[dstv[j] >> 8], 1);
            } else dstv[j] = -1;
        }
        __syncthreads();
        for (int i = tid; i < NB_COARSE; i += 256) {
            int c = lh[i];
            lbase[i] = (c > 0) ? (i * CAP + atomicAdd(&cursor[i], c)) : 0;
            lh[i] = 0;                        // becomes local cursor
        }
        __syncthreads();
        #pragma unroll
        for (int j = 0; j < EPB / 256; j++) {
            if (dstv[j] >= 0) {
                int b = dstv[j] >> 8;
                int pos = lbase[b] + atomicAdd(&lh[b], 1);
                part[pos] = ((unsigned int)(dstv[j] & 255) << 24) | (unsigned int)srcv[j];
            }
        }
        return;
    }

    // ---------- GEMM1 role: h = bf16(x @ W1) ----------
    typedef ushort (*tile_t)[136];
    tile_t As = (tile_t)smem;
    tile_t Bs = (tile_t)(smem + 128 * 136);
    int row0 = (blockIdx.x - NBLK_E) * 128;
    const int M = N_NODES;

    #pragma unroll
    for (int i = 0; i < 16; i++) {
        int li = tid + i * 256;
        int r = li >> 5, c4 = li & 31;
        int grow = row0 + r; if (grow > M - 1) grow = M - 1;
        float4 v = *(const float4*)(x + (size_t)grow * 128 + c4 * 4);
        ushort4 o;
        o.x = f2b(v.x); o.y = f2b(v.y); o.z = f2b(v.z); o.w = f2b(v.w);
        *(ushort4*)&As[r][c4 * 4] = o;
    }
    #pragma unroll
    for (int i = 0; i < 16; i++) {
        int li = tid + i * 256;
        int k = li >> 5, n4 = li & 31;
        float4 v = *(const float4*)(W1 + (size_t)k * 128 + n4 * 4);
        Bs[n4 * 4 + 0][k] = f2b(v.x);
        Bs[n4 * 4 + 1][k] = f2b(v.y);
        Bs[n4 * 4 + 2][k] = f2b(v.z);
        Bs[n4 * 4 + 3][k] = f2b(v.w);
    }
    __syncthreads();

    int wave = tid >> 6, lane = tid & 63;
    int lr = lane & 15, lq = lane >> 4;
    int wm0 = (wave & 1) * 64;
    int wn0 = (wave >> 1) * 64;

    f4_t acc[4][4];
    #pragma unroll
    for (int mi = 0; mi < 4; mi++)
        #pragma unroll
        for (int ni = 0; ni < 4; ni++) acc[mi][ni] = (f4_t){0.f, 0.f, 0.f, 0.f};

    #pragma unroll
    for (int kb = 0; kb < 4; kb++) {
        bf8_t af[4], bfr[4];
        #pragma unroll
        for (int mi = 0; mi < 4; mi++)
            af[mi] = *(const bf8_t*)&As[wm0 + mi * 16 + lr][kb * 32 + lq * 8];
        #pragma unroll
        for (int ni = 0; ni < 4; ni++)
            bfr[ni] = *(const bf8_t*)&Bs[wn0 + ni * 16 + lr][kb * 32 + lq * 8];
        #pragma unroll
        for (int mi = 0; mi < 4; mi++)
            #pragma unroll
            for (int ni = 0; ni < 4; ni++)
                acc[mi][ni] = __builtin_amdgcn_mfma_f32_16x16x32_bf16(
                    af[mi], bfr[ni], acc[mi][ni], 0, 0, 0);
    }

    #pragma unroll
    for (int mi = 0; mi < 4; mi++) {
        #pragma unroll
        for (int r = 0; r < 4; r++) {
            int row = row0 + wm0 + mi * 16 + lq * 4 + r;
            if (row < M) {
                #pragma unroll
                for (int ni = 0; ni < 4; ni++)
                    h[(size_t)row * 128 + wn0 + ni * 16 + lr] = f2b(acc[mi][ni][r]);
            }
        }
    }
}

// ------- per-bucket CSR finalize: padded per-node ranges (pad -> sentinel N_NODES) -------
// dinv has N_NODES+1 entries; dinv[N_NODES]=0 makes pad contributions exactly 0.

__global__ __launch_bounds__(256) void k_csr(const unsigned int* __restrict__ part,
                                             const int* __restrict__ cursor,
                                             int* __restrict__ offs,
                                             int* __restrict__ pcnt,
                                             float* __restrict__ dinv,
                                             int* __restrict__ ssrc) {
    __shared__ int ldeg[256], lsc[256], lcur[256], sob[256];
    __shared__ unsigned int stage[CAP];
    int t = threadIdx.x;
    int b = blockIdx.x;
    int rbeg = b * CAP;
    int cnt = cursor[b];              // edges landed in this bucket (offset-from-base)
    int node0 = b << 8;
    if (b == 0 && t == 0) dinv[N_NODES] = 0.f;   // sentinel weight
    ldeg[t] = 0;
    __syncthreads();
    for (int i = t; i < cnt; i += 256) {
        unsigned int u = part[rbeg + i];
        stage[i] = u;
        atomicAdd(&ldeg[u >> 24], 1);
    }
    __syncthreads();
    int v = ldeg[t];
    int pv = (v + 7) & ~7;            // padded to multiple of 8
    lsc[t] = pv;
    __syncthreads();
    for (int off = 1; off < 256; off <<= 1) {
        int add = (t >= off) ? lsc[t - off] : 0;
        __syncthreads();
        lsc[t] += add;
        __syncthreads();
    }
    int ob = b * PCAP + (lsc[t] - pv);   // padded output base for node (node0+t)
    sob[t] = ob;
    lcur[t] = 0;
    if (node0 + t < N_NODES) {
        offs[node0 + t] = ob;
        pcnt[node0 + t] = pv;
        dinv[node0 + t] = rsqrtf((float)(v + 1));   // +1: self-loop
    }
    __syncthreads();
    for (int i = t; i < cnt; i += 256) {
        unsigned int u = stage[i];
        int d = u >> 24;
        int pos = atomicAdd(&lcur[d], 1);
        ssrc[sob[d] + pos] = (int)(u & 0xFFFFFFu);
    }
    for (int i = v; i < pv; i++) ssrc[ob + i] = N_NODES;   // sentinel pads (dinv=0)
}

// -------- aggregation: h2[n] = bf16(relu(b1 + dinv[n]*(h[n]*dinv[n] + sum_s h[s]*dinv[s]))) ----
// One wave per node (R4 layout). dinv applied per edge (wave-uniform 4B broadcast
// loads). Edge lists padded to multiples of 8 with sentinel N_NODES (dinv=0).

__global__ __launch_bounds__(256) void k_agg(const ushort* __restrict__ h,
                                             const int* __restrict__ offs,
                                             const int* __restrict__ pcnt,
                                             const int* __restrict__ ssrc,
                                             const float* __restrict__ dinv,
                                             const float* __restrict__ b1,
                                             ushort* __restrict__ h2) {
    int wave = threadIdx.x >> 6;
    int lane = threadIdx.x & 63;
    int n = blockIdx.x * 4 + wave;
    if (n >= N_NODES) return;

    const unsigned int* hp = (const unsigned int*)h;  // 2 bf16 per uint, 64 uints/row
    int e0 = offs[n];
    int iters = pcnt[n] >> 3;
    const uint4* ip = (const uint4*)(ssrc + e0);      // 32B-aligned (e0 mult of 8)

    float ax0 = 0.f, ay0 = 0.f, ax1 = 0.f, ay1 = 0.f;
    float ax2 = 0.f, ay2 = 0.f, ax3 = 0.f, ay3 = 0.f;
    uint4 i0, i1;
    if (iters > 0) { i0 = ip[0]; i1 = ip[1]; }
    for (int it = 0; it < iters; it++) {
        uint4 nx0 = i0, nx1 = i1;
        if (it + 1 < iters) { nx0 = ip[(it + 1) * 2]; nx1 = ip[(it + 1) * 2 + 1]; }
        float w0 = dinv[i0.x], w1 = dinv[i0.y], w2 = dinv[i0.z], w3 = dinv[i0.w];
        float w4 = dinv[i1.x], w5 = dinv[i1.y], w6 = dinv[i1.z], w7 = dinv[i1.w];
        unsigned int u0 = hp[i0.x * 64 + lane];
        unsigned int u1 = hp[i0.y * 64 + lane];
        unsigned int u2 = hp[i0.z * 64 + lane];
        unsigned int u3 = hp[i0.w * 64 + lane];
        unsigned int u4 = hp[i1.x * 64 + lane];
        unsigned int u5 = hp[i1.y * 64 + lane];
        unsigned int u6 = hp[i1.z * 64 + lane];
        unsigned int u7 = hp[i1.w * 64 + lane];
        ax0 = fmaf(b2f_lo(u0), w0, ax0); ay0 = fmaf(b2f_hi(u0), w0, ay0);
        ax1 = fmaf(b2f_lo(u1), w1, ax1); ay1 = fmaf(b2f_hi(u1), w1, ay1);
        ax2 = fmaf(b2f_lo(u2), w2, ax2); ay2 = fmaf(b2f_hi(u2), w2, ay2);
        ax3 = fmaf(b2f_lo(u3), w3, ax3); ay3 = fmaf(b2f_hi(u3), w3, ay3);
        ax0 = fmaf(b2f_lo(u4), w4, ax0); ay0 = fmaf(b2f_hi(u4), w4, ay0);
        ax1 = fmaf(b2f_lo(u5), w5, ax1); ay1 = fmaf(b2f_hi(u5), w5, ay1);
        ax2 = fmaf(b2f_lo(u6), w6, ax2); ay2 = fmaf(b2f_hi(u6), w6, ay2);
        ax3 = fmaf(b2f_lo(u7), w7, ax3); ay3 = fmaf(b2f_hi(u7), w7, ay3);
        i0 = nx0; i1 = nx1;
    }
    unsigned int us = hp[(size_t)n * 64 + lane];      // self term (unscaled)
    float dn = dinv[n];
    float rx = (ax0 + ax1 + ax2 + ax3 + b2f_lo(us) * dn) * dn;
    float ry = (ay0 + ay1 + ay2 + ay3 + b2f_hi(us) * dn) * dn;
    float2 bb = ((const float2*)b1)[lane];
    rx += bb.x; ry += bb.y;
    rx = rx > 0.f ? rx : 0.f;
    ry = ry > 0.f ? ry : 0.f;
    unsigned int o = ((unsigned int)f2b(ry) << 16) | (unsigned int)f2b(rx);
    ((unsigned int*)h2)[(size_t)n * 64 + lane] = o;
}

// ---------------- bf16 MFMA GEMM2: out = h2 @ W2 + b2 (fp32 out) ----------------

__global__ __launch_bounds__(256, 2) void k_mfma2(const ushort* __restrict__ A,
                                                  const float* __restrict__ W,
                                                  const float* __restrict__ bias,
                                                  float* __restrict__ C, int M) {
    constexpr int BM = 128, KK = 128, PAD = 8, BN = 64, MF = 2, NF = 4;
    __shared__ ushort As[BM][KK + PAD];
    __shared__ ushort Bs[BN][KK + PAD];

    int tid = threadIdx.x;
    int row0 = blockIdx.x * BM;

    #pragma unroll
    for (int i = 0; i < 8; i++) {
        int li = tid + i * 256;           // 128*16 uint4 loads
        int r = li >> 4, c8 = li & 15;
        int grow = row0 + r; if (grow > M - 1) grow = M - 1;
        uint4 v = *(const uint4*)(A + (size_t)grow * KK + c8 * 8);
        *(uint4*)&As[r][c8 * 8] = v;
    }
    #pragma unroll
    for (int i = 0; i < 8; i++) {
        int li = tid + i * 256;           // 128*16 float4 loads
        int k = li >> 4, n4 = li & 15;
        float4 v = *(const float4*)(W + (size_t)k * BN + n4 * 4);
        Bs[n4 * 4 + 0][k] = f2b(v.x);
        Bs[n4 * 4 + 1][k] = f2b(v.y);
        Bs[n4 * 4 + 2][k] = f2b(v.z);
        Bs[n4 * 4 + 3][k] = f2b(v.w);
    }
    __syncthreads();

    int wave = tid >> 6, lane = tid & 63;
    int lr = lane & 15, lq = lane >> 4;
    int wm0 = wave * 32;

    f4_t acc[MF][NF];
    #pragma unroll
    for (int mi = 0; mi < MF; mi++)
        #pragma unroll
        for (int ni = 0; ni < NF; ni++) acc[mi][ni] = (f4_t){0.f, 0.f, 0.f, 0.f};

    #pragma unroll
    for (int kb = 0; kb < 4; kb++) {
        bf8_t af[MF], bfr[NF];
        #pragma unroll
        for (int mi = 0; mi < MF; mi++)
            af[mi] = *(const bf8_t*)&As[wm0 + mi * 16 + lr][kb * 32 + lq * 8];
        #pragma unroll
        for (int ni = 0; ni < NF; ni++)
            bfr[ni] = *(const bf8_t*)&Bs[ni * 16 + lr][kb * 32 + lq * 8];
        #pragma unroll
        for (int mi = 0; mi < MF; mi++)
            #pragma unroll
            for (int ni = 0; ni < NF; ni++)
                acc[mi][ni] = __builtin_amdgcn_mfma_f32_16x16x32_bf16(
                    af[mi], bfr[ni], acc[mi][ni], 0, 0, 0);
    }

    #pragma unroll
    for (int mi = 0; mi < MF; mi++) {
        #pragma unroll
        for (int r = 0; r < 4; r++) {
            int row = row0 + wm0 + mi * 16 + lq * 4 + r;
            if (row < M) {
                #pragma unroll
                for (int ni = 0; ni < NF; ni++) {
                    int col = ni * 16 + lr;
                    C[(size_t)row * BN + col] = acc[mi][ni][r] + bias[col];
                }
            }
        }
    }
}

// ---------------- launch ----------------

extern "C" void kernel_launch(void* const* d_in, const int* in_sizes, int n_in,
                              void* d_out, int out_size, void* d_ws, size_t ws_size,
                              hipStream_t stream) {
    const float* x  = (const float*)d_in[0];
    const float* W1 = (const float*)d_in[1];
    const float* b1 = (const float*)d_in[2];
    const float* W2 = (const float*)d_in[3];
    const float* b2 = (const float*)d_in[4];
    const int*   ei = (const int*)d_in[5];
    float* out = (float*)d_out;

    char* w = (char*)d_ws;
    size_t off = 0;
    auto alloc = [&](size_t bytes) -> void* {
        void* p = w + off;
        off += (bytes + 255) & ~(size_t)255;
        return p;
    };
    ushort* h      = (ushort*)alloc((size_t)(N_NODES + 1) * HIDDEN * 2);  // +1 sentinel row
    ushort* h2     = (ushort*)alloc((size_t)N_NODES * HIDDEN * 2);
    float* dinv    = (float*)alloc((size_t)(N_NODES + 1) * 4);   // +1: dinv[N]=0 sentinel
    int*   offs    = (int*)alloc((size_t)N_NODES * 4);
    int*   pcnt    = (int*)alloc((size_t)N_NODES * 4);
    int*   ssrc    = (int*)alloc((size_t)NB_COARSE * PCAP * 4);
    unsigned int* part = (unsigned int*)alloc((size_t)NB_COARSE * CAP * 4);
    int*   cursor  = (int*)alloc((size_t)NB_COARSE * 4);

    hipMemsetAsync(cursor, 0, (size_t)NB_COARSE * 4, stream);
    k_fuse1<<<NBLK_E + GB1, 256, 0, stream>>>(ei, cursor, part, x, W1, h);
    k_csr<<<NB_COARSE, 256, 0, stream>>>(part, cursor, offs, pcnt, dinv, ssrc);
    k_agg<<<(N_NODES + 3) / 4, 256, 0, stream>>>(h, offs, pcnt, ssrc, dinv, b1, h2);
    k_mfma2<<<GB1, 256, 0, stream>>>(h2, W2, b2, out, N_NODES);
}

// Round 9
// 219.931 us; speedup vs baseline: 1.1347x; 1.0270x over previous
//
#include <hip/hip_runtime.h>

#define N_NODES 100000
#define N_EDGES 1600000
#define IN_DIM  128
#define HIDDEN  128
#define OUT_DIM 64

#define NB_COARSE ((N_NODES + 255) / 256)   // 391 coarse buckets (256 nodes each)
#define EPB 4096                            // edges per block in partition role
#define NBLK_E ((N_EDGES + EPB - 1) / EPB)  // 391 partition blocks
#define GB1 ((N_NODES + 127) / 128)         // 782 GEMM1 blocks
#define CAP 5120                            // fixed bucket capacity (mean 4092 + 16 sigma)
#define PCAP 6912                           // padded bucket capacity, mult of 8

typedef __attribute__((ext_vector_type(8))) short bf8_t;   // 8 x bf16 (4 VGPRs)
typedef __attribute__((ext_vector_type(4))) float f4_t;    // MFMA accumulator

__device__ __forceinline__ ushort f2b(float f) {           // fp32 -> bf16 RNE
    unsigned int u = __float_as_uint(f);
    u += 0x7fffu + ((u >> 16) & 1u);
    return (ushort)(u >> 16);
}
__device__ __forceinline__ float b2f_lo(unsigned int u) { return __uint_as_float(u << 16); }
__device__ __forceinline__ float b2f_hi(unsigned int u) { return __uint_as_float(u & 0xffff0000u); }

// ---- fused launch 1: partition role (blocks 0..390) + GEMM1 role (391..1172) ----
// h is UNSCALED bf16 (dinv applied per-edge in k_agg2).

__global__ __launch_bounds__(256, 2) void k_fuse1(const int* __restrict__ ei,
                                                  int* __restrict__ cursor,
                                                  unsigned int* __restrict__ part,
                                                  const float* __restrict__ x,
                                                  const float* __restrict__ W1,
                                                  ushort* __restrict__ h) {
    __shared__ __align__(16) ushort smem[2 * 128 * 136];   // 69632 B union
    int tid = threadIdx.x;

    if (blockIdx.x < NBLK_E) {
        // ---------- partition role ----------
        int* lh    = (int*)smem;             // local hist, then local cursor
        int* lbase = lh + NB_COARSE;         // global base of this block's run
        for (int i = tid; i < NB_COARSE; i += 256) lh[i] = 0;
        __syncthreads();
        int e0 = blockIdx.x * EPB;
        int srcv[EPB / 256], dstv[EPB / 256];
        #pragma unroll
        for (int j = 0; j < EPB / 256; j++) {
            int e = e0 + j * 256 + tid;
            if (e < N_EDGES) {
                srcv[j] = ei[e];
                dstv[j] = ei[N_EDGES + e];
                atomicAdd(&lh[dstv[j] >> 8], 1);
            } else dstv[j] = -1;
        }
        __syncthreads();
        for (int i = tid; i < NB_COARSE; i += 256) {
            int c = lh[i];
            lbase[i] = (c > 0) ? (i * CAP + atomicAdd(&cursor[i], c)) : 0;
            lh[i] = 0;                        // becomes local cursor
        }
        __syncthreads();
        #pragma unroll
        for (int j = 0; j < EPB / 256; j++) {
            if (dstv[j] >= 0) {
                int b = dstv[j] >> 8;
                int pos = lbase[b] + atomicAdd(&lh[b], 1);
                part[pos] = ((unsigned int)(dstv[j] & 255) << 24) | (unsigned int)srcv[j];
            }
        }
        return;
    }

    // ---------- GEMM1 role: h = bf16(x @ W1) ----------
    typedef ushort (*tile_t)[136];
    tile_t As = (tile_t)smem;
    tile_t Bs = (tile_t)(smem + 128 * 136);
    int row0 = (blockIdx.x - NBLK_E) * 128;
    const int M = N_NODES;

    #pragma unroll
    for (int i = 0; i < 16; i++) {
        int li = tid + i * 256;
        int r = li >> 5, c4 = li & 31;
        int grow = row0 + r; if (grow > M - 1) grow = M - 1;
        float4 v = *(const float4*)(x + (size_t)grow * 128 + c4 * 4);
        ushort4 o;
        o.x = f2b(v.x); o.y = f2b(v.y); o.z = f2b(v.z); o.w = f2b(v.w);
        *(ushort4*)&As[r][c4 * 4] = o;
    }
    #pragma unroll
    for (int i = 0; i < 16; i++) {
        int li = tid + i * 256;
        int k = li >> 5, n4 = li & 31;
        float4 v = *(const float4*)(W1 + (size_t)k * 128 + n4 * 4);
        Bs[n4 * 4 + 0][k] = f2b(v.x);
        Bs[n4 * 4 + 1][k] = f2b(v.y);
        Bs[n4 * 4 + 2][k] = f2b(v.z);
        Bs[n4 * 4 + 3][k] = f2b(v.w);
    }
    __syncthreads();

    int wave = tid >> 6, lane = tid & 63;
    int lr = lane & 15, lq = lane >> 4;
    int wm0 = (wave & 1) * 64;
    int wn0 = (wave >> 1) * 64;

    f4_t acc[4][4];
    #pragma unroll
    for (int mi = 0; mi < 4; mi++)
        #pragma unroll
        for (int ni = 0; ni < 4; ni++) acc[mi][ni] = (f4_t){0.f, 0.f, 0.f, 0.f};

    #pragma unroll
    for (int kb = 0; kb < 4; kb++) {
        bf8_t af[4], bfr[4];
        #pragma unroll
        for (int mi = 0; mi < 4; mi++)
            af[mi] = *(const bf8_t*)&As[wm0 + mi * 16 + lr][kb * 32 + lq * 8];
        #pragma unroll
        for (int ni = 0; ni < 4; ni++)
            bfr[ni] = *(const bf8_t*)&Bs[wn0 + ni * 16 + lr][kb * 32 + lq * 8];
        #pragma unroll
        for (int mi = 0; mi < 4; mi++)
            #pragma unroll
            for (int ni = 0; ni < 4; ni++)
                acc[mi][ni] = __builtin_amdgcn_mfma_f32_16x16x32_bf16(
                    af[mi], bfr[ni], acc[mi][ni], 0, 0, 0);
    }

    #pragma unroll
    for (int mi = 0; mi < 4; mi++) {
        #pragma unroll
        for (int r = 0; r < 4; r++) {
            int row = row0 + wm0 + mi * 16 + lq * 4 + r;
            if (row < M) {
                #pragma unroll
                for (int ni = 0; ni < 4; ni++)
                    h[(size_t)row * 128 + wn0 + ni * 16 + lr] = f2b(acc[mi][ni][r]);
            }
        }
    }
}

// ------- per-bucket CSR finalize: padded per-node ranges (pad -> sentinel N_NODES) -------

__global__ __launch_bounds__(256) void k_csr(const unsigned int* __restrict__ part,
                                             const int* __restrict__ cursor,
                                             int* __restrict__ offs,
                                             int* __restrict__ pcnt,
                                             float* __restrict__ dinv,
                                             int* __restrict__ ssrc) {
    __shared__ int ldeg[256], lsc[256], lcur[256], sob[256];
    __shared__ unsigned int stage[CAP];
    int t = threadIdx.x;
    int b = blockIdx.x;
    int rbeg = b * CAP;
    int cnt = cursor[b];              // edges landed in this bucket (offset-from-base)
    int node0 = b << 8;
    if (b == 0 && t == 0) dinv[N_NODES] = 0.f;   // sentinel weight
    ldeg[t] = 0;
    __syncthreads();
    for (int i = t; i < cnt; i += 256) {
        unsigned int u = part[rbeg + i];
        stage[i] = u;
        atomicAdd(&ldeg[u >> 24], 1);
    }
    __syncthreads();
    int v = ldeg[t];
    int pv = (v + 7) & ~7;            // padded to multiple of 8
    lsc[t] = pv;
    __syncthreads();
    for (int off = 1; off < 256; off <<= 1) {
        int add = (t >= off) ? lsc[t - off] : 0;
        __syncthreads();
        lsc[t] += add;
        __syncthreads();
    }
    int ob = b * PCAP + (lsc[t] - pv);   // padded output base for node (node0+t)
    sob[t] = ob;
    lcur[t] = 0;
    if (node0 + t < N_NODES) {
        offs[node0 + t] = ob;
        pcnt[node0 + t] = pv;
        dinv[node0 + t] = rsqrtf((float)(v + 1));   // +1: self-loop
    }
    __syncthreads();
    for (int i = t; i < cnt; i += 256) {
        unsigned int u = stage[i];
        int d = u >> 24;
        int pos = atomicAdd(&lcur[d], 1);
        ssrc[sob[d] + pos] = (int)(u & 0xFFFFFFu);
    }
    for (int i = v; i < pv; i++) ssrc[ob + i] = N_NODES;   // sentinel pads (dinv=0)
}

// ---- fused aggregation + GEMM2: out[n] = relu(b1 + dinv[n]*(sum h[s]*dinv[s] + h[n]*dinv[n])) @ W2 + b2 ----
// 256-thr block = 4 waves, 16 nodes. Wave w aggregates nodes w*4..w*4+3 (R4-proven
// gather loop), writes bf16 h2 rows into a 16x128 LDS tile. Then one barrier and
// each wave MFMAs its 16-column slice of out. LDS ~22 KB -> ~7 blocks/CU.

__global__ __launch_bounds__(256, 6) void k_agg2(const ushort* __restrict__ h,
                                                 const int* __restrict__ offs,
                                                 const int* __restrict__ pcnt,
                                                 const int* __restrict__ ssrc,
                                                 const float* __restrict__ dinv,
                                                 const float* __restrict__ b1,
                                                 const float* __restrict__ W2,
                                                 const float* __restrict__ b2,
                                                 float* __restrict__ out) {
    __shared__ ushort As[16][136];    // aggregated h2 rows (bf16)
    __shared__ ushort Bs[64][136];    // W2 n-major (bf16)
    int tid = threadIdx.x;
    int wave = tid >> 6, lane = tid & 63;
    int base = blockIdx.x * 16;       // N_NODES divisible by 16

    // stage W2 (128x64 fp32 -> Bs[n][k] bf16)
    #pragma unroll
    for (int i = 0; i < 8; i++) {
        int li = tid + i * 256;
        int k = li >> 4, n4 = li & 15;
        float4 v = *(const float4*)(W2 + (size_t)k * 64 + n4 * 4);
        Bs[n4 * 4 + 0][k] = f2b(v.x);
        Bs[n4 * 4 + 1][k] = f2b(v.y);
        Bs[n4 * 4 + 2][k] = f2b(v.z);
        Bs[n4 * 4 + 3][k] = f2b(v.w);
    }

    const unsigned int* hp = (const unsigned int*)h;  // 2 bf16 per uint, 64 uints/row
    float2 bb = ((const float2*)b1)[lane];

    #pragma unroll 1
    for (int j = 0; j < 4; j++) {
        int r = wave * 4 + j;         // row in As
        int n = base + r;
        int e0 = offs[n];
        int iters = pcnt[n] >> 3;
        const uint4* ip = (const uint4*)(ssrc + e0);  // 32B-aligned

        float ax0 = 0.f, ay0 = 0.f, ax1 = 0.f, ay1 = 0.f;
        float ax2 = 0.f, ay2 = 0.f, ax3 = 0.f, ay3 = 0.f;
        uint4 i0, i1;
        if (iters > 0) { i0 = ip[0]; i1 = ip[1]; }
        for (int it = 0; it < iters; it++) {
            uint4 nx0 = i0, nx1 = i1;
            if (it + 1 < iters) { nx0 = ip[(it + 1) * 2]; nx1 = ip[(it + 1) * 2 + 1]; }
            float w0 = dinv[i0.x], w1 = dinv[i0.y], w2 = dinv[i0.z], w3 = dinv[i0.w];
            float w4 = dinv[i1.x], w5 = dinv[i1.y], w6 = dinv[i1.z], w7 = dinv[i1.w];
            unsigned int u0 = hp[i0.x * 64 + lane];
            unsigned int u1 = hp[i0.y * 64 + lane];
            unsigned int u2 = hp[i0.z * 64 + lane];
            unsigned int u3 = hp[i0.w * 64 + lane];
            unsigned int u4 = hp[i1.x * 64 + lane];
            unsigned int u5 = hp[i1.y * 64 + lane];
            unsigned int u6 = hp[i1.z * 64 + lane];
            unsigned int u7 = hp[i1.w * 64 + lane];
            ax0 = fmaf(b2f_lo(u0), w0, ax0); ay0 = fmaf(b2f_hi(u0), w0, ay0);
            ax1 = fmaf(b2f_lo(u1), w1, ax1); ay1 = fmaf(b2f_hi(u1), w1, ay1);
            ax2 = fmaf(b2f_lo(u2), w2, ax2); ay2 = fmaf(b2f_hi(u2), w2, ay2);
            ax3 = fmaf(b2f_lo(u3), w3, ax3); ay3 = fmaf(b2f_hi(u3), w3, ay3);
            ax0 = fmaf(b2f_lo(u4), w4, ax0); ay0 = fmaf(b2f_hi(u4), w4, ay0);
            ax1 = fmaf(b2f_lo(u5), w5, ax1); ay1 = fmaf(b2f_hi(u5), w5, ay1);
            ax2 = fmaf(b2f_lo(u6), w6, ax2); ay2 = fmaf(b2f_hi(u6), w6, ay2);
            ax3 = fmaf(b2f_lo(u7), w7, ax3); ay3 = fmaf(b2f_hi(u7), w7, ay3);
            i0 = nx0; i1 = nx1;
        }
        unsigned int us = hp[(size_t)n * 64 + lane];  // self term (unscaled)
        float dn = dinv[n];
        float rx = (ax0 + ax1 + ax2 + ax3 + b2f_lo(us) * dn) * dn + bb.x;
        float ry = (ay0 + ay1 + ay2 + ay3 + b2f_hi(us) * dn) * dn + bb.y;
        rx = rx > 0.f ? rx : 0.f;
        ry = ry > 0.f ? ry : 0.f;
        *(unsigned int*)&As[r][lane * 2] =
            ((unsigned int)f2b(ry) << 16) | (unsigned int)f2b(rx);
    }
    __syncthreads();

    // GEMM2 phase: wave w -> out cols [w*16, w*16+16), rows = the 16 nodes
    int lr = lane & 15, lq = lane >> 4;
    f4_t acc = (f4_t){0.f, 0.f, 0.f, 0.f};
    #pragma unroll
    for (int kb = 0; kb < 4; kb++) {
        bf8_t af = *(const bf8_t*)&As[lr][kb * 32 + lq * 8];
        bf8_t bf = *(const bf8_t*)&Bs[wave * 16 + lr][kb * 32 + lq * 8];
        acc = __builtin_amdgcn_mfma_f32_16x16x32_bf16(af, bf, acc, 0, 0, 0);
    }
    int col = wave * 16 + lr;
    float bv = b2[col];
    #pragma unroll
    for (int r = 0; r < 4; r++) {
        int node = base + lq * 4 + r;
        out[(size_t)node * 64 + col] = acc[r] + bv;
    }
}

// ---------------- launch ----------------

extern "C" void kernel_launch(void* const* d_in, const int* in_sizes, int n_in,
                              void* d_out, int out_size, void* d_ws, size_t ws_size,
                              hipStream_t stream) {
    const float* x  = (const float*)d_in[0];
    const float* W1 = (const float*)d_in[1];
    const float* b1 = (const float*)d_in[2];
    const float* W2 = (const float*)d_in[3];
    const float* b2 = (const float*)d_in[4];
    const int*   ei = (const int*)d_in[5];
    float* out = (float*)d_out;

    char* w = (char*)d_ws;
    size_t off = 0;
    auto alloc = [&](size_t bytes) -> void* {
        void* p = w + off;
        off += (bytes + 255) & ~(size_t)255;
        return p;
    };
    ushort* h      = (ushort*)alloc((size_t)(N_NODES + 1) * HIDDEN * 2);  // +1 sentinel row
    float* dinv    = (float*)alloc((size_t)(N_NODES + 1) * 4);   // +1: dinv[N]=0 sentinel
    int*   offs    = (int*)alloc((size_t)N_NODES * 4);
    int*   pcnt    = (int*)alloc((size_t)N_NODES * 4);
    int*   ssrc    = (int*)alloc((size_t)NB_COARSE * PCAP * 4);
    unsigned int* part = (unsigned int*)alloc((size_t)NB_COARSE * CAP * 4);
    int*   cursor  = (int*)alloc((size_t)NB_COARSE * 4);

    hipMemsetAsync(cursor, 0, (size_t)NB_COARSE * 4, stream);
    k_fuse1<<<NBLK_E + GB1, 256, 0, stream>>>(ei, cursor, part, x, W1, h);
    k_csr<<<NB_COARSE, 256, 0, stream>>>(part, cursor, offs, pcnt, dinv, ssrc);
    k_agg2<<<N_NODES / 16, 256, 0, stream>>>(h, offs, pcnt, ssrc, dinv, b1, W2, b2, out);
}